// Round 6
// baseline (246.507 us; speedup 1.0000x reference)
//
#include <hip/hip_runtime.h>

#define B_ 8
#define T_ 2048
#define C_ 1024
#define D_ 128

typedef __attribute__((ext_vector_type(4))) float f32x4;
typedef __attribute__((ext_vector_type(8))) short s16x8;

static __device__ __forceinline__ ushort f2bf(float f){
  unsigned u = __float_as_uint(f);
  u = (u + 0x7fffu + ((u >> 16) & 1u)) >> 16;   // RNE
  return (ushort)u;
}
static __device__ __forceinline__ float bf2f(ushort u){
  return __uint_as_float(((unsigned)u) << 16);
}
static __device__ __forceinline__ unsigned cvt_pk_bf16(float lo, float hi){
  unsigned r;
  asm volatile("v_cvt_pk_bf16_f32 %0, %1, %2" : "=v"(r) : "v"(lo), "v"(hi));
  return r;
}

// ---------------------------------------------------------------------------
// Kernel 1: wprep — W{q,k,v} f32 -> wt[384][1024] bf16 (transposed)
// ---------------------------------------------------------------------------
__global__ __launch_bounds__(256) void wprep_kernel(
    const float* __restrict__ Wk, const float* __restrict__ Wq, const float* __restrict__ Wv,
    ushort* __restrict__ wt)
{
  int j = blockIdx.x * 256 + threadIdx.x;     // 393,216 = 384*1024
  int n3 = j >> 10, k = j & 1023;
  int sel = n3 >> 7, n = n3 & 127;
  const float* W = (sel == 0) ? Wq : (sel == 1) ? Wk : Wv;
  wt[j] = f2bf(W[k * 128 + n]);               // wt[n3][k] = W[k][n]
}

// ---------------------------------------------------------------------------
// Kernel 2: qkv GEMM + RoPE. NO LDS, NO BARRIERS: fragments loaded straight
// from global (A: f32 x + cvt_pk in-flight; B: wt, L2-resident). 8 free-running
// waves per block; compiler software-pipelines the k-loop.
// 512 thr (8 waves = 2m x 4n), tile 64x384.
// ---------------------------------------------------------------------------
__global__ __launch_bounds__(512) void qkv_kernel(
    const float* __restrict__ x, const ushort* __restrict__ wt,
    const float* __restrict__ cosp, const float* __restrict__ sinp,
    ushort* __restrict__ Qw, ushort* __restrict__ Kw, ushort* __restrict__ VT)
{
  const int tid = threadIdx.x;
  const int m0  = blockIdx.x * 64;
  const int wid = tid >> 6, lane = tid & 63;
  const int wm = wid >> 2, wn = wid & 3;
  const int g = lane >> 4, l15 = lane & 15;

  f32x4 acc[2][6];
  #pragma unroll
  for (int i = 0; i < 2; i++)
    #pragma unroll
    for (int j = 0; j < 6; j++) acc[i][j] = f32x4{0.f, 0.f, 0.f, 0.f};

  // A: row = m0 + wm*32 + mi*16 + l15, k = k0 + kk*32 + g*8 (8 f32 -> bf16x8)
  const float*  xA = x  + (size_t)(m0 + wm * 32 + l15) * 1024 + g * 8;
  // B: col = wn*96 + n*16 + l15, k likewise (16B contiguous in wt)
  const ushort* wB = wt + (size_t)(wn * 96 + l15) * 1024 + g * 8;

  #pragma unroll 2
  for (int k0 = 0; k0 < 1024; k0 += 64) {
    #pragma unroll
    for (int kk = 0; kk < 2; kk++) {
      const int ko = k0 + kk * 32;
      s16x8 af[2];
      #pragma unroll
      for (int mi = 0; mi < 2; mi++) {
        f32x4 a0 = *(const f32x4*)(xA + mi * 16384 + ko);
        f32x4 a1 = *(const f32x4*)(xA + mi * 16384 + ko + 4);
        unsigned aw[4];
        aw[0] = cvt_pk_bf16(a0[0], a0[1]);
        aw[1] = cvt_pk_bf16(a0[2], a0[3]);
        aw[2] = cvt_pk_bf16(a1[0], a1[1]);
        aw[3] = cvt_pk_bf16(a1[2], a1[3]);
        af[mi] = *(s16x8*)aw;
      }
      s16x8 bfr[6];
      #pragma unroll
      for (int n = 0; n < 6; n++)
        bfr[n] = *(const s16x8*)(wB + (size_t)n * 16384 + ko);
      #pragma unroll
      for (int mi = 0; mi < 2; mi++)
        #pragma unroll
        for (int n = 0; n < 6; n++)
          acc[mi][n] = __builtin_amdgcn_mfma_f32_16x16x32_bf16(af[mi], bfr[n], acc[mi][n], 0, 0, 0);
    }
  }

  // epilogue: C frag = (row = m0+wm*32+mi*16+g*4+r, col = wn*96+n*16+l15)
  const int rowb0 = m0 + wm * 32;
  #pragma unroll
  for (int mi = 0; mi < 2; mi++) {
    #pragma unroll
    for (int n = 0; n < 6; n++) {
      int colbase = wn * 96 + n * 16;
      int region  = colbase >> 7;            // 0=q 1=k 2=v
      int dcol    = (colbase & 127) + l15;
      int rowb    = rowb0 + mi * 16 + g * 4;
      if (region < 2) {
        ushort* dst = region ? Kw : Qw;
        int ii = dcol >> 1;
        float sgn = (dcol & 1) ? 1.0f : -1.0f;
        #pragma unroll
        for (int r = 0; r < 4; r++) {
          float own  = acc[mi][n][r];
          float part = __shfl_xor(own, 1, 64);
          int row = rowb + r;
          int t   = row & 2047;
          float c = cosp[t * 64 + ii], s = sinp[t * 64 + ii];
          float val = own * c + sgn * part * s;
          dst[row * 128 + dcol] = f2bf(val);
        }
      } else {
        int t0 = rowb & 2047;
        int b  = rowb >> 11;
        unsigned w0 = (unsigned)f2bf(acc[mi][n][0]) | ((unsigned)f2bf(acc[mi][n][1]) << 16);
        unsigned w1 = (unsigned)f2bf(acc[mi][n][2]) | ((unsigned)f2bf(acc[mi][n][3]) << 16);
        uint2 st; st.x = w0; st.y = w1;
        *(uint2*)(VT + (size_t)b * (128 * 2048) + dcol * 2048 + t0) = st;  // VT[b][d][t]
      }
    }
  }
}

// ---------------------------------------------------------------------------
// Kernel 3: split-KV causal flash attention. NO LDS, NO BARRIERS.
// 2304 independent waves; wave = (batch b, q-tile of 32 rows, kv-chunk <=256).
// XCD pinning: b = bid & 7 -> each XCD's L2 caches exactly one batch's K/V.
// K/V fragments read directly from L2. 576 blocks x 256 thr.
// ---------------------------------------------------------------------------
__global__ __launch_bounds__(256) void attn_kernel(
    const ushort* __restrict__ Qw, const ushort* __restrict__ Kw,
    const ushort* __restrict__ VT, ushort* __restrict__ Opart,
    float* __restrict__ Ml)
{
  const int tid = threadIdx.x;
  const int w = tid >> 6, lane = tid & 63;
  const int g = lane >> 4, l15 = lane & 15;

  const int bid = blockIdx.x;
  const int b    = bid & 7;                  // XCD pin
  const int item = (bid >> 3) * 4 + w;       // 0..287 within batch
  int a = 0;
  #pragma unroll
  for (int t = 1; t < 8; t++) if (item >= 4 * t * (t + 1)) a = t;
  const int r0  = item - 4 * a * (a + 1);
  const int jin = r0 / (a + 1);
  const int c   = r0 - jin * (a + 1);
  const int j   = a * 8 + jin;               // q-tile 0..63
  const int q0  = j * 32;
  const int kv_base = c * 256;
  const int kv_end  = min(kv_base + 256, q0 + 32);
  const int nt  = (kv_end - kv_base + 63) >> 6;   // 64-row kv tiles (tail masked)
  int qg[2];
  qg[0] = q0 + l15;
  qg[1] = q0 + 16 + l15;

  const ushort* Qb = Qw + (size_t)b * T_ * 128;
  const ushort* Kb = Kw + (size_t)b * T_ * 128;
  const ushort* Vb = VT + (size_t)b * 128 * T_;

  s16x8 qf[2][4];
  #pragma unroll
  for (int i = 0; i < 2; i++)
    #pragma unroll
    for (int kd = 0; kd < 4; kd++)
      qf[i][kd] = *(const s16x8*)(Qb + (size_t)qg[i] * 128 + kd * 32 + g * 8);

  f32x4 acco[2][8];
  #pragma unroll
  for (int i = 0; i < 2; i++)
    #pragma unroll
    for (int d = 0; d < 8; d++) acco[i][d] = f32x4{0.f, 0.f, 0.f, 0.f};
  float mrun[2] = {-1e30f, -1e30f}, lrun[2] = {0.f, 0.f};
  const float scale = 0.08838834764831845f;   // 1/sqrt(128)

  for (int t = 0; t < nt; t++) {
    const int kv0 = kv_base + t * 64;

    // QK^T (swapped): accs[i][h] = S^T[kv=h*16+g*4+r][q=l15] for q-frag i
    f32x4 accs[2][4];
    #pragma unroll
    for (int i = 0; i < 2; i++)
      #pragma unroll
      for (int h = 0; h < 4; h++) accs[i][h] = f32x4{0.f, 0.f, 0.f, 0.f};
    #pragma unroll
    for (int h = 0; h < 4; h++) {
      const ushort* kr = Kb + (size_t)(kv0 + h * 16 + l15) * 128 + g * 8;
      #pragma unroll
      for (int kd = 0; kd < 4; kd++) {
        s16x8 kf = *(const s16x8*)(kr + kd * 32);
        accs[0][h] = __builtin_amdgcn_mfma_f32_16x16x32_bf16(kf, qf[0][kd], accs[0][h], 0, 0, 0);
        accs[1][h] = __builtin_amdgcn_mfma_f32_16x16x32_bf16(kf, qf[1][kd], accs[1][h], 0, 0, 0);
      }
    }

    // online softmax per q-frag (16 kv/lane; reduce across g via shfl)
    s16x8 pbv[2][2];
    #pragma unroll
    for (int i = 0; i < 2; i++) {
      float p[4][4];
      float pmax = -1e30f;
      #pragma unroll
      for (int h = 0; h < 4; h++)
        #pragma unroll
        for (int r = 0; r < 4; r++) {
          int kvg = kv0 + h * 16 + g * 4 + r;
          float sv = accs[i][h][r] * scale;
          sv = (kvg <= qg[i]) ? sv : -1e30f;
          p[h][r] = sv;
          pmax = fmaxf(pmax, sv);
        }
      pmax = fmaxf(pmax, __shfl_xor(pmax, 16, 64));
      pmax = fmaxf(pmax, __shfl_xor(pmax, 32, 64));
      float mnew = fmaxf(mrun[i], pmax);
      float f = __expf(mrun[i] - mnew);
      float psum = 0.0f;
      #pragma unroll
      for (int h = 0; h < 4; h++)
        #pragma unroll
        for (int r = 0; r < 4; r++) { float e = __expf(p[h][r] - mnew); p[h][r] = e; psum += e; }
      psum += __shfl_xor(psum, 16, 64);
      psum += __shfl_xor(psum, 32, 64);
      lrun[i] = lrun[i] * f + psum;
      mrun[i] = mnew;
      #pragma unroll
      for (int d = 0; d < 8; d++) acco[i][d] *= f;

      // P remap -> two B-fragments (kv 0..31, 32..63 of tile)
      #pragma unroll
      for (int hk = 0; hk < 2; hk++) {
        unsigned v0 = cvt_pk_bf16(p[2 * hk][0], p[2 * hk][1]);
        unsigned v1 = cvt_pk_bf16(p[2 * hk][2], p[2 * hk][3]);
        unsigned v2 = cvt_pk_bf16(p[2 * hk + 1][0], p[2 * hk + 1][1]);
        unsigned v3 = cvt_pk_bf16(p[2 * hk + 1][2], p[2 * hk + 1][3]);
        unsigned pb[4];
        #pragma unroll
        for (int wd = 0; wd < 4; wd++) {
          int src = (((g & 1) * 2 + (wd >> 1)) << 4) + l15;
          unsigned t0 = __shfl((wd & 1) ? v1 : v0, src, 64);
          unsigned t1 = __shfl((wd & 1) ? v3 : v2, src, 64);
          pb[wd] = (g < 2) ? t0 : t1;
        }
        pbv[i][hk] = *(s16x8*)pb;
      }
    }

    // PV: acco[i][dt] = O^T[d=dt*16+g*4+r][q=l15]; V-frags direct from L2
    #pragma unroll
    for (int dt = 0; dt < 8; dt++) {
      const ushort* vr = Vb + (size_t)(dt * 16 + l15) * 2048 + kv0 + g * 8;
      s16x8 vf0 = *(const s16x8*)(vr);
      s16x8 vf1 = *(const s16x8*)(vr + 32);
      acco[0][dt] = __builtin_amdgcn_mfma_f32_16x16x32_bf16(vf0, pbv[0][0], acco[0][dt], 0, 0, 0);
      acco[0][dt] = __builtin_amdgcn_mfma_f32_16x16x32_bf16(vf1, pbv[0][1], acco[0][dt], 0, 0, 0);
      acco[1][dt] = __builtin_amdgcn_mfma_f32_16x16x32_bf16(vf0, pbv[1][0], acco[1][dt], 0, 0, 0);
      acco[1][dt] = __builtin_amdgcn_mfma_f32_16x16x32_bf16(vf1, pbv[1][1], acco[1][dt], 0, 0, 0);
    }
  }

  // store l-normalized partial (bf16) + (m,l); slot = b*288 + item
  const int slot = b * 288 + item;
  #pragma unroll
  for (int i = 0; i < 2; i++) {
    float inv = 1.0f / lrun[i];
    ushort* ob = Opart + (size_t)slot * 4096 + (i * 16 + l15) * 128;
    #pragma unroll
    for (int dt = 0; dt < 8; dt++) {
      f32x4 o4 = acco[i][dt] * inv;
      uint2 st;
      st.x = cvt_pk_bf16(o4[0], o4[1]);
      st.y = cvt_pk_bf16(o4[2], o4[3]);
      *(uint2*)(ob + dt * 16 + g * 4) = st;
    }
    if (lane < 16) {
      Ml[(size_t)slot * 64 + (i * 16 + lane) * 2]     = mrun[i];
      Ml[(size_t)slot * 64 + (i * 16 + lane) * 2 + 1] = lrun[i];
    }
  }
}

// ---------------------------------------------------------------------------
// Kernel 4: combine partials. Block (256 thr) per (b, 32-row q-tile).
// ---------------------------------------------------------------------------
__global__ __launch_bounds__(256) void combine_kernel(
    const ushort* __restrict__ Opart, const float* __restrict__ Ml,
    float* __restrict__ out)
{
  const int bq = blockIdx.x;          // 0..511
  const int b = bq >> 6, j = bq & 63;
  const int a = j >> 3, jin = j & 7, nch = a + 1;
  const int s0 = b * 288 + 4 * a * (a + 1) + jin * (a + 1);
  const int tid = threadIdx.x;
  const int row = tid >> 3, ci = tid & 7;

  float M = -1e30f;
  for (int c = 0; c < nch; c++)
    M = fmaxf(M, Ml[(size_t)(s0 + c) * 64 + row * 2]);

  float acc[16];
  #pragma unroll
  for (int k = 0; k < 16; k++) acc[k] = 0.f;
  float W = 0.f;
  for (int c = 0; c < nch; c++) {
    float m = Ml[(size_t)(s0 + c) * 64 + row * 2];
    float l = Ml[(size_t)(s0 + c) * 64 + row * 2 + 1];
    float wgt = l * __expf(m - M);
    W += wgt;
    const ushort* vp = Opart + (size_t)(s0 + c) * 4096 + row * 128 + ci * 16;
    s16x8 v0 = *(const s16x8*)vp;
    s16x8 v1 = *(const s16x8*)(vp + 8);
    #pragma unroll
    for (int k = 0; k < 8; k++) {
      acc[k]     += wgt * bf2f((ushort)v0[k]);
      acc[8 + k] += wgt * bf2f((ushort)v1[k]);
    }
  }
  float invW = 1.0f / W;
  float* op = out + ((size_t)(b * 2048 + j * 32 + row)) * 128 + ci * 16;
  #pragma unroll
  for (int q = 0; q < 4; q++) {
    f32x4 o4 { acc[q*4]*invW, acc[q*4+1]*invW, acc[q*4+2]*invW, acc[q*4+3]*invW };
    *(f32x4*)(op + q * 4) = o4;
  }
}

// ---------------------------------------------------------------------------
extern "C" void kernel_launch(void* const* d_in, const int* in_sizes, int n_in,
                              void* d_out, int out_size, void* d_ws, size_t ws_size,
                              hipStream_t stream)
{
  const float* x    = (const float*)d_in[0];
  const float* cosp = (const float*)d_in[1];
  const float* sinp = (const float*)d_in[2];
  const float* Wk   = (const float*)d_in[3];
  const float* Wq   = (const float*)d_in[4];
  const float* Wv   = (const float*)d_in[5];
  char* ws = (char*)d_ws;
  ushort* wt    = (ushort*)ws;                       //    786,432 B
  ushort* Qw    = (ushort*)(ws + 1048576);           //  4,194,304 B
  ushort* Kw    = (ushort*)(ws + 5242880);           //  4,194,304 B
  ushort* VT    = (ushort*)(ws + 9437184);           //  4,194,304 B
  ushort* Opart = (ushort*)(ws + 13631488);          // 18,874,368 B (2304 slots x 8 KB)
  float*  Ml    = (float*)(ws + 32505856);           //    589,824 B
  float* outp = (float*)d_out;

  wprep_kernel<<<1536, 256, 0, stream>>>(Wk, Wq, Wv, wt);
  qkv_kernel<<<256, 512, 0, stream>>>(x, wt, cosp, sinp, Qw, Kw, VT);
  attn_kernel<<<576, 256, 0, stream>>>(Qw, Kw, VT, Opart, Ml);
  combine_kernel<<<512, 256, 0, stream>>>(Opart, Ml, outp);
}

// Round 7
// 172.587 us; speedup vs baseline: 1.4283x; 1.4283x over previous
//
#include <hip/hip_runtime.h>

#define B_ 8
#define T_ 2048
#define C_ 1024
#define D_ 128

typedef __attribute__((ext_vector_type(4))) float f32x4;
typedef __attribute__((ext_vector_type(8))) short s16x8;

static __device__ __forceinline__ ushort f2bf(float f){
  unsigned u = __float_as_uint(f);
  u = (u + 0x7fffu + ((u >> 16) & 1u)) >> 16;   // RNE
  return (ushort)u;
}
static __device__ __forceinline__ float bf2f(ushort u){
  return __uint_as_float(((unsigned)u) << 16);
}
static __device__ __forceinline__ unsigned cvt_pk_bf16(float lo, float hi){
  unsigned r;
  asm volatile("v_cvt_pk_bf16_f32 %0, %1, %2" : "=v"(r) : "v"(lo), "v"(hi));
  return r;
}

// ---------------------------------------------------------------------------
// Kernel 1: wprep — W{q,k,v} f32 -> wt[384][1024] bf16 (transposed)
// ---------------------------------------------------------------------------
__global__ __launch_bounds__(256) void wprep_kernel(
    const float* __restrict__ Wk, const float* __restrict__ Wq, const float* __restrict__ Wv,
    ushort* __restrict__ wt)
{
  int j = blockIdx.x * 256 + threadIdx.x;     // 393,216 = 384*1024
  int n3 = j >> 10, k = j & 1023;
  int sel = n3 >> 7, n = n3 & 127;
  const float* W = (sel == 0) ? Wq : (sel == 1) ? Wk : Wv;
  wt[j] = f2bf(W[k * 128 + n]);               // wt[n3][k] = W[k][n]
}

// ---------------------------------------------------------------------------
// Kernel 2: qkv GEMM + RoPE. Block = (64 rows, 192 cols), BK=64, 512 blocks
// x 512 thr (8 waves = 2m x 4n). LDS 64 KB -> 2 blocks/CU (fixes the 1-block
// occupancy cap of rounds 3-6). Double-buffered, prologue-shifted staging.
// A: reg-staged from f32 x (cvt in-flight, swizzled ds_write).
// B: global_load_lds, 3 x 64-col swizzled panels.
// ---------------------------------------------------------------------------
__global__ __launch_bounds__(512) void qkv_kernel(
    const float* __restrict__ x, const ushort* __restrict__ wt,
    const float* __restrict__ cosp, const float* __restrict__ sinp,
    ushort* __restrict__ Qw, ushort* __restrict__ Kw, ushort* __restrict__ VT)
{
  __shared__ __align__(16) ushort As[2][64 * 64];    // 2 x  8 KB
  __shared__ __align__(16) ushort Bs[2][192 * 64];   // 2 x 24 KB
  const int tid = threadIdx.x;
  const int bid = blockIdx.x;
  const int m0  = (bid >> 1) * 64;
  const int h   = bid & 1;                  // col half: cols [h*192, h*192+192)
  const int wid = tid >> 6, lane = tid & 63;
  const int wm = wid >> 2, wn = wid & 3;
  const int g = lane >> 4, l15 = lane & 15;

  f32x4 acc[2][3];
  #pragma unroll
  for (int i = 0; i < 2; i++)
    #pragma unroll
    for (int j = 0; j < 3; j++) acc[i][j] = f32x4{0.f, 0.f, 0.f, 0.f};

  // B staging: thread t fills LDS bytes [t*16, t*16+16) of each 64-col panel
  const int o = tid * 16;
  const int srow = o >> 7;
  const int scb  = (o & 127) ^ ((srow & 7) << 4);
  const char* wbase = (const char*)wt + (size_t)(h * 192 + srow) * 2048 + scb;
  // A staging: thread t loads 8 f32 of row (t>>3), col chunk (t&7)*8
  const int arow = tid >> 3;
  const float* xp = x + (size_t)(m0 + arow) * 1024 + (tid & 7) * 8;
  const int adst = arow * 64 + (((tid & 7) * 8) ^ ((arow & 7) << 3));  // ushort units

  auto stageB = [&](int k0, int bb) {
    #pragma unroll
    for (int j = 0; j < 3; j++) {
      __builtin_amdgcn_global_load_lds(
          (const __attribute__((address_space(1))) void*)(wbase + (size_t)j * 64 * 2048 + k0 * 2),
          (__attribute__((address_space(3))) void*)((char*)Bs + bb * 24576 + j * 8192 + o), 16, 0, 0);
    }
  };
  auto writeA = [&](f32x4 a0, f32x4 a1, int bb) {
    unsigned aw[4];
    aw[0] = cvt_pk_bf16(a0[0], a0[1]);
    aw[1] = cvt_pk_bf16(a0[2], a0[3]);
    aw[2] = cvt_pk_bf16(a1[0], a1[1]);
    aw[3] = cvt_pk_bf16(a1[2], a1[3]);
    *(s16x8*)(&As[bb][adst]) = *(s16x8*)aw;
  };

  {
    f32x4 a0 = *(const f32x4*)(xp);
    f32x4 a1 = *(const f32x4*)(xp + 4);
    stageB(0, 0);
    writeA(a0, a1, 0);
  }
  __syncthreads();
  int bb = 0;
  for (int k0 = 0; k0 < 1024; k0 += 64) {
    int k1 = (k0 + 64 < 1024) ? k0 + 64 : 0;       // last iter: harmless reload
    f32x4 n0 = *(const f32x4*)(xp + k1);
    f32x4 n1 = *(const f32x4*)(xp + k1 + 4);
    stageB(k1, bb ^ 1);

    const char* Ab = (const char*)As + bb * 8192;
    const char* Bb = (const char*)Bs + bb * 24576;
    #pragma unroll
    for (int kk = 0; kk < 2; kk++) {
      s16x8 af[2];
      #pragma unroll
      for (int mi = 0; mi < 2; mi++) {
        int row = wm * 32 + mi * 16 + l15;
        int cb  = (kk * 64 + g * 16) ^ ((row & 7) << 4);
        af[mi] = *(const s16x8*)(Ab + row * 128 + cb);
      }
      s16x8 bfr[3];
      #pragma unroll
      for (int n = 0; n < 3; n++) {
        int col = wn * 48 + n * 16 + l15;
        int cb2 = (kk * 64 + g * 16) ^ ((col & 7) << 4);
        bfr[n] = *(const s16x8*)(Bb + col * 128 + cb2);
      }
      __builtin_amdgcn_s_setprio(1);
      #pragma unroll
      for (int mi = 0; mi < 2; mi++)
        #pragma unroll
        for (int n = 0; n < 3; n++)
          acc[mi][n] = __builtin_amdgcn_mfma_f32_16x16x32_bf16(af[mi], bfr[n], acc[mi][n], 0, 0, 0);
      __builtin_amdgcn_s_setprio(0);
    }
    writeA(n0, n1, bb ^ 1);
    __syncthreads();
    bb ^= 1;
  }

  // epilogue: C frag = (row = m0+wm*32+mi*16+g*4+r, col = h*192+wn*48+n*16+l15)
  const int rowb0 = m0 + wm * 32;
  #pragma unroll
  for (int mi = 0; mi < 2; mi++) {
    #pragma unroll
    for (int n = 0; n < 3; n++) {
      int colbase = h * 192 + wn * 48 + n * 16;
      int region  = colbase >> 7;            // 0=q 1=k 2=v
      int dcol    = (colbase & 127) + l15;
      int rowb    = rowb0 + mi * 16 + g * 4;
      if (region < 2) {
        ushort* dst = region ? Kw : Qw;
        int ii = dcol >> 1;
        float sgn = (dcol & 1) ? 1.0f : -1.0f;
        #pragma unroll
        for (int r = 0; r < 4; r++) {
          float own  = acc[mi][n][r];
          float part = __shfl_xor(own, 1, 64);
          int row = rowb + r;
          int t   = row & 2047;
          float c = cosp[t * 64 + ii], s = sinp[t * 64 + ii];
          float val = own * c + sgn * part * s;
          dst[row * 128 + dcol] = f2bf(val);
        }
      } else {
        int t0 = rowb & 2047;
        int b  = rowb >> 11;
        unsigned w0 = (unsigned)f2bf(acc[mi][n][0]) | ((unsigned)f2bf(acc[mi][n][1]) << 16);
        unsigned w1 = (unsigned)f2bf(acc[mi][n][2]) | ((unsigned)f2bf(acc[mi][n][3]) << 16);
        uint2 st; st.x = w0; st.y = w1;
        *(uint2*)(VT + (size_t)b * (128 * 2048) + dcol * 2048 + t0) = st;  // VT[b][d][t]
      }
    }
  }
}

// ---------------------------------------------------------------------------
// Kernel 3: split-KV causal flash attention (round-5 known-good). Block =
// (b, q-block of 128 rows [32/wave, 2 frags], kv-chunk of 256). KVBLK=64,
// double-buffered LDS K/V^T. 576 blocks x 256 thr.
// ---------------------------------------------------------------------------
__global__ __launch_bounds__(256) void attn_kernel(
    const ushort* __restrict__ Qw, const ushort* __restrict__ Kw,
    const ushort* __restrict__ VT, ushort* __restrict__ Opart,
    float* __restrict__ Ml)
{
  __shared__ __align__(16) ushort KVs[2][16384];   // per buf: K 16 KB + V^T 16 KB
  const int tid = threadIdx.x;
  const int w = tid >> 6, lane = tid & 63;
  const int g = lane >> 4, l15 = lane & 15;

  const int bid = blockIdx.x;
  const int b   = bid / 72;
  const int idx = bid - b * 72;
  int a = 0;
  #pragma unroll
  for (int t = 1; t < 8; t++) if (idx >= t * (t + 1)) a = t;
  const int rem = idx - a * (a + 1);
  const int jin = rem / (a + 1);
  const int c   = rem - jin * (a + 1);
  const int j   = 2 * a + jin;
  const int q0  = j * 128;
  const int kv_base = c * 256;
  const int kv_end  = min(kv_base + 256, q0 + 128);
  const int nt  = (kv_end - kv_base) >> 6;     // 1..4 full 64-row tiles
  int qg[2];
  qg[0] = q0 + w * 32 + l15;
  qg[1] = qg[0] + 16;

  const ushort* Qb = Qw + (size_t)b * T_ * 128;
  const char* Kbase = (const char*)(Kw + (size_t)b * T_ * 128);
  const char* Vbase = (const char*)(VT + (size_t)b * 128 * T_);

  auto stage = [&](int kv0, int bbuf) {
    char* Kd = (char*)&KVs[bbuf][0];
    char* Vd = (char*)&KVs[bbuf][8192];
    #pragma unroll
    for (int p = 0; p < 4; p++) {           // K: 64 rows x 256B, swizzled
      int oo = p * 4096 + tid * 16;
      int r = oo >> 8, cin = oo & 255;
      int cb = cin ^ ((r & 7) << 4);
      __builtin_amdgcn_global_load_lds(
          (const __attribute__((address_space(1))) void*)(Kbase + (size_t)(kv0 + r) * 256 + cb),
          (__attribute__((address_space(3))) void*)(Kd + oo), 16, 0, 0);
    }
    #pragma unroll
    for (int p = 0; p < 4; p++) {           // V^T: 128 rows x 128B, swizzled
      int oo = p * 4096 + tid * 16;
      int r = oo >> 7, cin = oo & 127;
      int cb = cin ^ ((r & 7) << 4);
      __builtin_amdgcn_global_load_lds(
          (const __attribute__((address_space(1))) void*)(Vbase + (size_t)r * 4096 + (size_t)kv0 * 2 + cb),
          (__attribute__((address_space(3))) void*)(Vd + oo), 16, 0, 0);
    }
  };

  s16x8 qf[2][4];
  #pragma unroll
  for (int i = 0; i < 2; i++)
    #pragma unroll
    for (int kd = 0; kd < 4; kd++)
      qf[i][kd] = *(const s16x8*)(Qb + (size_t)qg[i] * 128 + kd * 32 + g * 8);

  f32x4 acco[2][8];
  #pragma unroll
  for (int i = 0; i < 2; i++)
    #pragma unroll
    for (int d = 0; d < 8; d++) acco[i][d] = f32x4{0.f, 0.f, 0.f, 0.f};
  float mrun[2] = {-1e30f, -1e30f}, lrun[2] = {0.f, 0.f};
  const float scale = 0.08838834764831845f;   // 1/sqrt(128)

  stage(kv_base, 0);
  __syncthreads();
  int bbuf = 0;
  for (int t = 0; t < nt; t++) {
    int kv0 = kv_base + t * 64;
    if (t + 1 < nt) stage(kv0 + 64, bbuf ^ 1);
    const char* Kd = (const char*)&KVs[bbuf][0];
    const char* Vd = (const char*)&KVs[bbuf][8192];

    // QK^T (swapped): accs[i][h] = S^T[kv=h*16+g*4+r][q=l15] for q-frag i
    f32x4 accs[2][4];
    #pragma unroll
    for (int i = 0; i < 2; i++)
      #pragma unroll
      for (int h = 0; h < 4; h++) accs[i][h] = f32x4{0.f, 0.f, 0.f, 0.f};
    __builtin_amdgcn_s_setprio(1);
    #pragma unroll
    for (int h = 0; h < 4; h++) {
      int rr = h * 16 + l15;
      int rs = rr * 256;
      int sw = (rr & 7) << 4;
      #pragma unroll
      for (int kd = 0; kd < 4; kd++) {
        s16x8 kf = *(const s16x8*)(Kd + rs + ((kd * 64 + g * 16) ^ sw));
        accs[0][h] = __builtin_amdgcn_mfma_f32_16x16x32_bf16(kf, qf[0][kd], accs[0][h], 0, 0, 0);
        accs[1][h] = __builtin_amdgcn_mfma_f32_16x16x32_bf16(kf, qf[1][kd], accs[1][h], 0, 0, 0);
      }
    }
    __builtin_amdgcn_s_setprio(0);

    // online softmax (per q-frag): 16 kv values/lane, reduce across g via shfl
    s16x8 pbv[2][2];
    #pragma unroll
    for (int i = 0; i < 2; i++) {
      float p[4][4];
      float pmax = -1e30f;
      #pragma unroll
      for (int h = 0; h < 4; h++)
        #pragma unroll
        for (int r = 0; r < 4; r++) {
          int kvg = kv0 + h * 16 + g * 4 + r;
          float sv = accs[i][h][r] * scale;
          sv = (kvg <= qg[i]) ? sv : -1e30f;
          p[h][r] = sv;
          pmax = fmaxf(pmax, sv);
        }
      pmax = fmaxf(pmax, __shfl_xor(pmax, 16, 64));
      pmax = fmaxf(pmax, __shfl_xor(pmax, 32, 64));
      float mnew = fmaxf(mrun[i], pmax);
      float f = __expf(mrun[i] - mnew);
      float psum = 0.0f;
      #pragma unroll
      for (int h = 0; h < 4; h++)
        #pragma unroll
        for (int r = 0; r < 4; r++) { float e = __expf(p[h][r] - mnew); p[h][r] = e; psum += e; }
      psum += __shfl_xor(psum, 16, 64);
      psum += __shfl_xor(psum, 32, 64);
      lrun[i] = lrun[i] * f + psum;
      mrun[i] = mnew;
      #pragma unroll
      for (int d = 0; d < 8; d++) acco[i][d] *= f;

      // P remap -> two B-fragments (kv 0..31, 32..63 of tile)
      #pragma unroll
      for (int hk = 0; hk < 2; hk++) {
        unsigned v0 = cvt_pk_bf16(p[2 * hk][0], p[2 * hk][1]);
        unsigned v1 = cvt_pk_bf16(p[2 * hk][2], p[2 * hk][3]);
        unsigned v2 = cvt_pk_bf16(p[2 * hk + 1][0], p[2 * hk + 1][1]);
        unsigned v3 = cvt_pk_bf16(p[2 * hk + 1][2], p[2 * hk + 1][3]);
        unsigned pb[4];
        #pragma unroll
        for (int wd = 0; wd < 4; wd++) {
          int src = (((g & 1) * 2 + (wd >> 1)) << 4) + l15;
          unsigned t0 = __shfl((wd & 1) ? v1 : v0, src, 64);
          unsigned t1 = __shfl((wd & 1) ? v3 : v2, src, 64);
          pb[wd] = (g < 2) ? t0 : t1;
        }
        pbv[i][hk] = *(s16x8*)pb;
      }
    }

    // PV: acco[i][dt] = O^T[d=dt*16+g*4+r][q=l15]; V-frags shared across i
    __builtin_amdgcn_s_setprio(1);
    #pragma unroll
    for (int dt = 0; dt < 8; dt++) {
      int rr = dt * 16 + l15;
      int rs = rr * 128;
      int sw = (rr & 7) << 4;
      s16x8 vf0 = *(const s16x8*)(Vd + rs + ((g * 16) ^ sw));
      s16x8 vf1 = *(const s16x8*)(Vd + rs + ((64 + g * 16) ^ sw));
      acco[0][dt] = __builtin_amdgcn_mfma_f32_16x16x32_bf16(vf0, pbv[0][0], acco[0][dt], 0, 0, 0);
      acco[0][dt] = __builtin_amdgcn_mfma_f32_16x16x32_bf16(vf1, pbv[0][1], acco[0][dt], 0, 0, 0);
      acco[1][dt] = __builtin_amdgcn_mfma_f32_16x16x32_bf16(vf0, pbv[1][0], acco[1][dt], 0, 0, 0);
      acco[1][dt] = __builtin_amdgcn_mfma_f32_16x16x32_bf16(vf1, pbv[1][1], acco[1][dt], 0, 0, 0);
    }
    __builtin_amdgcn_s_setprio(0);
    __syncthreads();
    bbuf ^= 1;
  }

  // store l-normalized partials (bf16) + (m,l); partial slot == bid
  #pragma unroll
  for (int i = 0; i < 2; i++) {
    float inv = 1.0f / lrun[i];
    ushort* ob = Opart + (size_t)bid * 16384 + (w * 32 + i * 16 + l15) * 128;
    #pragma unroll
    for (int dt = 0; dt < 8; dt++) {
      f32x4 o4 = acco[i][dt] * inv;
      uint2 st;
      st.x = cvt_pk_bf16(o4[0], o4[1]);
      st.y = cvt_pk_bf16(o4[2], o4[3]);
      *(uint2*)(ob + dt * 16 + g * 4) = st;
    }
    if (lane < 16) {
      Ml[(size_t)bid * 256 + (w * 32 + i * 16 + lane) * 2]     = mrun[i];
      Ml[(size_t)bid * 256 + (w * 32 + i * 16 + lane) * 2 + 1] = lrun[i];
    }
  }
}

// ---------------------------------------------------------------------------
// Kernel 4: combine partials. Block (512 thr) per (b, 64-row half of q-block).
// ---------------------------------------------------------------------------
__global__ __launch_bounds__(512) void combine_kernel(
    const ushort* __restrict__ Opart, const float* __restrict__ Ml,
    float* __restrict__ out)
{
  const int bq = blockIdx.x;          // 0..255
  const int b = bq >> 5, h = bq & 31;
  const int j = h >> 1, half = h & 1;
  const int a = j >> 1, jin = j & 1, nch = a + 1;
  const int s0 = b * 72 + a * (a + 1) + jin * (a + 1);
  const int tid = threadIdx.x;
  const int row = half * 64 + (tid >> 3), ci = tid & 7;

  float M = -1e30f;
  for (int c = 0; c < nch; c++)
    M = fmaxf(M, Ml[(size_t)(s0 + c) * 256 + row * 2]);

  float acc[16];
  #pragma unroll
  for (int k = 0; k < 16; k++) acc[k] = 0.f;
  float W = 0.f;
  for (int c = 0; c < nch; c++) {
    float m = Ml[(size_t)(s0 + c) * 256 + row * 2];
    float l = Ml[(size_t)(s0 + c) * 256 + row * 2 + 1];
    float wgt = l * __expf(m - M);
    W += wgt;
    const ushort* vp = Opart + (size_t)(s0 + c) * 16384 + row * 128 + ci * 16;
    s16x8 v0 = *(const s16x8*)vp;
    s16x8 v1 = *(const s16x8*)(vp + 8);
    #pragma unroll
    for (int k = 0; k < 8; k++) {
      acc[k]     += wgt * bf2f((ushort)v0[k]);
      acc[8 + k] += wgt * bf2f((ushort)v1[k]);
    }
  }
  float invW = 1.0f / W;
  float* op = out + ((size_t)(b * 2048 + h * 64 + (tid >> 3))) * 128 + ci * 16;
  #pragma unroll
  for (int q = 0; q < 4; q++) {
    f32x4 o4 { acc[q*4]*invW, acc[q*4+1]*invW, acc[q*4+2]*invW, acc[q*4+3]*invW };
    *(f32x4*)(op + q * 4) = o4;
  }
}

// ---------------------------------------------------------------------------
extern "C" void kernel_launch(void* const* d_in, const int* in_sizes, int n_in,
                              void* d_out, int out_size, void* d_ws, size_t ws_size,
                              hipStream_t stream)
{
  const float* x    = (const float*)d_in[0];
  const float* cosp = (const float*)d_in[1];
  const float* sinp = (const float*)d_in[2];
  const float* Wk   = (const float*)d_in[3];
  const float* Wq   = (const float*)d_in[4];
  const float* Wv   = (const float*)d_in[5];
  char* ws = (char*)d_ws;
  ushort* wt    = (ushort*)ws;                       //    786,432 B
  ushort* Qw    = (ushort*)(ws + 1048576);           //  4,194,304 B
  ushort* Kw    = (ushort*)(ws + 5242880);           //  4,194,304 B
  ushort* VT    = (ushort*)(ws + 9437184);           //  4,194,304 B
  ushort* Opart = (ushort*)(ws + 13631488);          // 18,874,368 B (576 slots x 32 KB)
  float*  Ml    = (float*)(ws + 32505856);           //    589,824 B
  float* outp = (float*)d_out;

  wprep_kernel<<<1536, 256, 0, stream>>>(Wk, Wq, Wv, wt);
  qkv_kernel<<<512, 512, 0, stream>>>(x, wt, cosp, sinp, Qw, Kw, VT);
  attn_kernel<<<576, 256, 0, stream>>>(Qw, Kw, VT, Opart, Ml);
  combine_kernel<<<256, 512, 0, stream>>>(Opart, Ml, outp);
}